// Round 4
// baseline (150.007 us; speedup 1.0000x reference)
//
#include <hip/hip_runtime.h>
#include <hip/hip_bf16.h>
#include <cstdint>
#include <cstddef>

#define SDIM 4096
#define CDIM 256
#define HSZ (64 * 4096)  // shorts per 64x4096 panel

typedef __attribute__((ext_vector_type(8))) short bf16x8;
typedef __attribute__((ext_vector_type(8))) __bf16 bfv8;
typedef __attribute__((ext_vector_type(4))) float f32x4;
typedef __attribute__((ext_vector_type(16))) float f32x16;
typedef __attribute__((ext_vector_type(2))) short short2v;

__device__ __forceinline__ short bfc(float f) { return __builtin_bit_cast(short, (__bf16)f); }
__device__ __forceinline__ short4 pk4(float a, float b, float c, float d) {
  short4 r; r.x = bfc(a); r.y = bfc(b); r.z = bfc(c); r.w = bfc(d); return r;
}
__device__ __forceinline__ unsigned pkbf(float lo, float hi) {
  unsigned ulo = (unsigned short)__builtin_bit_cast(short, (__bf16)lo);
  unsigned uhi = (unsigned short)__builtin_bit_cast(short, (__bf16)hi);
  return (uhi << 16) | ulo;
}
__device__ __forceinline__ f32x4 MFMA(bf16x8 a, bf16x8 b, f32x4 c) {
  return __builtin_amdgcn_mfma_f32_16x16x32_bf16(
      __builtin_bit_cast(bfv8, a), __builtin_bit_cast(bfv8, b), c, 0, 0, 0);
}
__device__ __forceinline__ f32x16 MFMA32(bf16x8 a, bf16x8 b, f32x16 c) {
  return __builtin_amdgcn_mfma_f32_32x32x16_bf16(
      __builtin_bit_cast(bfv8, a), __builtin_bit_cast(bfv8, b), c, 0, 0, 0);
}

// log2(e) / sqrt(256): folded into Q at GEMM epilogue; softmax uses exp2 directly.
#define SCQ 0.09016844f

// ---------------- weight fp32 -> bf16 ----------------
__global__ void cvt_weights_k(const float* __restrict__ wq, const float* __restrict__ wo,
                              short* __restrict__ wqb, short* __restrict__ wob) {
  int i = blockIdx.x * 256 + threadIdx.x;
  if (i < 768 * 256) wqb[i] = bfc(wq[i]);
  if (i < 256 * 256) wob[i] = bfc(wo[i]);
}

// ---------------- group norm -> normed^T[s][c] (bf16) ----------------
__global__ __launch_bounds__(256) void groupnorm_k(
    const float* __restrict__ x, const float* __restrict__ gamma,
    const float* __restrict__ beta, short* __restrict__ normedT) {
  int bg = blockIdx.x;  // b*32 + g
  int g = bg & 31, b = bg >> 5;
  const float* xg = x + (size_t)bg * 8 * SDIM;
  const float4* xv = (const float4*)xg;
  int tid = threadIdx.x;
  float sum = 0.f, sq = 0.f;
#pragma unroll 4
  for (int i = 0; i < 32; ++i) {
    float4 v = xv[tid + i * 256];
    sum += (v.x + v.y) + (v.z + v.w);
    sq += (v.x * v.x + v.y * v.y) + (v.z * v.z + v.w * v.w);
  }
#pragma unroll
  for (int m = 1; m < 64; m <<= 1) {
    sum += __shfl_xor(sum, m);
    sq += __shfl_xor(sq, m);
  }
  __shared__ float red[8];
  if ((tid & 63) == 0) { red[(tid >> 6) * 2] = sum; red[(tid >> 6) * 2 + 1] = sq; }
  __syncthreads();
  float s = red[0] + red[2] + red[4] + red[6];
  float q = red[1] + red[3] + red[5] + red[7];
  float mean = s * (1.f / 32768.f);
  float var = q * (1.f / 32768.f) - mean * mean;
  float rstd = rsqrtf(var + 1e-5f);
  float ga[8], be[8];
#pragma unroll
  for (int c = 0; c < 8; ++c) {
    ga[c] = gamma[g * 8 + c] * rstd;
    be[c] = beta[g * 8 + c] - mean * ga[c];
  }
  short* nt = normedT + (size_t)b * SDIM * CDIM + g * 8;
  for (int i = 0; i < 16; ++i) {
    int sidx = tid + i * 256;
    float v[8];
#pragma unroll
    for (int c = 0; c < 8; ++c) v[c] = xg[(size_t)c * SDIM + sidx] * ga[c] + be[c];
    union { short4 h[2]; bf16x8 v8; } o;
    o.h[0] = pk4(v[0], v[1], v[2], v[3]);
    o.h[1] = pk4(v[4], v[5], v[6], v[7]);
    *(bf16x8*)(nt + (size_t)sidx * CDIM) = o.v8;
  }
}

// ---------------- QKV GEMM (LDS-free): A=W rows, B=normed^T rows, D[o][s] ------------
__global__ __launch_bounds__(256) void gemm_qkv(const short* __restrict__ W,
                                                const short* __restrict__ XT,
                                                short* __restrict__ qkv) {
  int bx = blockIdx.x;           // o-block 0..11
  int by = blockIdx.y;           // s-block 0..63
  int bz = blockIdx.z;           // b
  int tid = threadIdx.x;
  int w = tid >> 6, lane = tid & 63;
  int sl = lane & 15, kg = lane >> 4;
  const short* Wr = W + (size_t)(bx * 64 + w * 16 + sl) * CDIM + kg * 8;
  const short* Xr = XT + ((size_t)bz * SDIM + by * 64 + sl) * CDIM + kg * 8;
  f32x4 zero = {0.f, 0.f, 0.f, 0.f};
  f32x4 acc[4] = {zero, zero, zero, zero};
#pragma unroll
  for (int kk = 0; kk < 8; ++kk) {
    bf16x8 a = *(const bf16x8*)(Wr + kk * 32);
#pragma unroll
    for (int nb = 0; nb < 4; ++nb) {
      bf16x8 bfr = *(const bf16x8*)(Xr + (size_t)nb * 16 * CDIM + kk * 32);
      acc[nb] = MFMA(a, bfr, acc[nb]);
    }
  }
  int n = bx / 3, sub = bx % 3;
  size_t hbase = (size_t)(bz * 4 + n) * 3 * HSZ;
  if (sub == 0) {
    short* qt = qkv + hbase;
#pragma unroll
    for (int nb = 0; nb < 4; ++nb) {
      int s = by * 64 + nb * 16 + sl;
      *(short4*)(qt + (size_t)s * 64 + w * 16 + kg * 4) =
          pk4(acc[nb][0] * SCQ, acc[nb][1] * SCQ, acc[nb][2] * SCQ, acc[nb][3] * SCQ);
    }
  } else if (sub == 1) {
    short* kt = qkv + hbase + HSZ;
#pragma unroll
    for (int nb = 0; nb < 4; ++nb) {
      int s = by * 64 + nb * 16 + sl;
      *(short4*)(kt + (size_t)s * 64 + w * 16 + kg * 4) =
          pk4(acc[nb][0], acc[nb][1], acc[nb][2], acc[nb][3]);
    }
  } else {
    short* vp = qkv + hbase + 2 * HSZ;
#pragma unroll
    for (int nb = 0; nb < 4; ++nb) {
      int s = by * 64 + nb * 16 + sl;
#pragma unroll
      for (int r = 0; r < 4; ++r)
        vp[(size_t)(w * 16 + kg * 4 + r) * SDIM + s] = bfc(acc[nb][r]);
    }
  }
}

// ---------------- flash attention: 1024 thr = 4 sgrp x 4 tq, 32x32x16 MFMA -----------
// Per wave: 32 s-cols, 1024 t (16 steps of 64). K^T frags from global (L1/L2);
// V staged in LDS (XOR swizzle); P stays in registers (pk + permlane32_swap).
// No online max (scores bounded, Q pre-scaled by log2e/16); exp2-domain softmax.
#define ZERO16 {0.f,0.f,0.f,0.f,0.f,0.f,0.f,0.f,0.f,0.f,0.f,0.f,0.f,0.f,0.f,0.f}
__global__ __launch_bounds__(1024, 4) void attn_k(const short* __restrict__ qkv,
                                                  short* __restrict__ attnoT) {
  __shared__ char smem_raw[34816];
  short* vlds = (short*)smem_raw;            // 4 tq tiles x 4096 shorts (32KB)
  float* accbuf = (float*)smem_raw;          // reused post-loop: 4*64*33 f32
  float* lbuf = (float*)(smem_raw + 33792);  // 4*32 f32

  int blk = blockIdx.x;
  int nb = blk & 7;      // (b*4+n) — grouped per XCD for L2 locality
  int sblk = blk >> 3;   // 0..31
  int tid = threadIdx.x;
  int w = tid >> 6, lane = tid & 63;
  int l5 = lane & 31, h = lane >> 5;
  int sgrp = w & 3, tq = w >> 2;

  size_t hbase = (size_t)nb * 3 * HSZ;
  const short* qt = qkv + hbase;
  const short* kt = qkv + hbase + HSZ;
  const short* vp = qkv + hbase + 2 * HSZ;

  int s0w = sblk * 128 + sgrp * 32;

  // Q fragments (B operand): n=s=l5, k=d
  bf16x8 qf[4];
#pragma unroll
  for (int kc = 0; kc < 4; ++kc)
    qf[kc] = *(const bf16x8*)(qt + (size_t)(s0w + l5) * 64 + kc * 16 + h * 8);

  // V staging ids (per tq group of 256 threads)
  int ltid = tid & 255;
  int sd = ltid >> 3;       // d row 0..31 (+32)
  int sc8 = ltid & 7;       // 8-short col chunk
  short* vtile = vlds + tq * 4096;
  int tbase = tq * 1024;
  int wc8 = (sc8 ^ (sd & 7)) * 8;

  bf16x8 vreg[2];
#pragma unroll
  for (int hh = 0; hh < 2; ++hh)
    vreg[hh] = *(const bf16x8*)(vp + (size_t)(sd + hh * 32) * SDIM + tbase + sc8 * 8);

  f32x16 acc_o0 = ZERO16, acc_o1 = ZERO16;
  float l_run = 0.f;
  int rc8 = (l5 & 7);  // read-swizzle component

  for (int step = 0; step < 16; ++step) {
    __syncthreads();
    *(bf16x8*)(vtile + sd * 64 + wc8) = vreg[0];
    *(bf16x8*)(vtile + (sd + 32) * 64 + wc8) = vreg[1];
    __syncthreads();
    int t0 = tbase + step * 64;
    if (step + 1 < 16) {
      int t1 = t0 + 64;
#pragma unroll
      for (int hh = 0; hh < 2; ++hh)
        vreg[hh] = *(const bf16x8*)(vp + (size_t)(sd + hh * 32) * SDIM + t1 + sc8 * 8);
    }

    // QK^T: A = K^T rows from global, B = Q regs. accs row = t-local.
    f32x16 accs0 = ZERO16, accs1 = ZERO16;
#pragma unroll
    for (int kc = 0; kc < 4; ++kc) {
      bf16x8 k0 = *(const bf16x8*)(kt + (size_t)(t0 + l5) * 64 + kc * 16 + h * 8);
      bf16x8 k1 = *(const bf16x8*)(kt + (size_t)(t0 + 32 + l5) * 64 + kc * 16 + h * 8);
      accs0 = MFMA32(k0, qf[kc], accs0);
      accs1 = MFMA32(k1, qf[kc], accs1);
    }

    // softmax: P = exp2(score), no max subtraction
    float p0[16], p1[16];
    float ts = 0.f;
#pragma unroll
    for (int r = 0; r < 16; ++r) { p0[r] = __builtin_amdgcn_exp2f(accs0[r]); ts += p0[r]; }
#pragma unroll
    for (int r = 0; r < 16; ++r) { p1[r] = __builtin_amdgcn_exp2f(accs1[r]); ts += p1[r]; }
    l_run += ts;

    // P -> A-frag via pack + permlane32_swap; PV: B = V rows from LDS
#define PV_TC(pp, tcb, tc)                                                        \
    {                                                                             \
      unsigned a0 = pkbf(pp[8 * tcb + 0], pp[8 * tcb + 1]);                       \
      unsigned a1 = pkbf(pp[8 * tcb + 2], pp[8 * tcb + 3]);                       \
      unsigned b0 = pkbf(pp[8 * tcb + 4], pp[8 * tcb + 5]);                       \
      unsigned b1 = pkbf(pp[8 * tcb + 6], pp[8 * tcb + 7]);                       \
      asm volatile("v_permlane32_swap_b32 %0, %1" : "+v"(a0), "+v"(b0));          \
      asm volatile("v_permlane32_swap_b32 %0, %1" : "+v"(a1), "+v"(b1));          \
      union { unsigned u[4]; bf16x8 v; } F;                                       \
      F.u[0] = a0; F.u[1] = a1; F.u[2] = b0; F.u[3] = b1;                         \
      int c8 = ((tc * 2 + h) ^ rc8) * 8;                                          \
      bf16x8 v0 = *(const bf16x8*)(vtile + l5 * 64 + c8);                         \
      bf16x8 v1 = *(const bf16x8*)(vtile + (32 + l5) * 64 + c8);                  \
      acc_o0 = MFMA32(F.v, v0, acc_o0);                                           \
      acc_o1 = MFMA32(F.v, v1, acc_o1);                                           \
    }
    PV_TC(p0, 0, 0)
    PV_TC(p0, 1, 1)
    PV_TC(p1, 0, 2)
    PV_TC(p1, 1, 3)
#undef PV_TC
  }

  l_run += __shfl_xor(l_run, 32);

  // cross-tq reduction through LDS (3 rounds), tq=0 accumulates
#pragma unroll
  for (int r = 1; r < 4; ++r) {
    __syncthreads();
    if (tq == r) {
      float* dst = accbuf + (size_t)(sgrp * 64 + lane) * 33;
#pragma unroll
      for (int i = 0; i < 16; ++i) { dst[i] = acc_o0[i]; dst[16 + i] = acc_o1[i]; }
      dst[32] = l_run;
    }
    __syncthreads();
    if (tq == 0) {
      const float* src = accbuf + (size_t)(sgrp * 64 + lane) * 33;
#pragma unroll
      for (int i = 0; i < 16; ++i) { acc_o0[i] += src[i]; acc_o1[i] += src[16 + i]; }
      l_run += src[32];
    }
  }
  if (tq == 0 && h == 0) lbuf[sgrp * 32 + l5] = l_run;
  __syncthreads();
  if (tq == 0) {
    int n = nb & 3, b = nb >> 2;
#pragma unroll
    for (int r = 0; r < 16; ++r) {
      int srow = (r & 3) + 8 * (r >> 2) + 4 * h;
      float inv = 1.f / lbuf[sgrp * 32 + srow];
      int sg = s0w + srow;
      size_t rowb = ((size_t)b * SDIM + sg) * CDIM + n * 64;
      attnoT[rowb + l5] = bfc(acc_o0[r] * inv);
      attnoT[rowb + 32 + l5] = bfc(acc_o1[r] * inv);
    }
  }
}

// ---------------- final GEMM (LDS-free): A=O^T rows, B=W_out rows, D[s][o] -----------
__global__ __launch_bounds__(256) void gemm_out(const short* __restrict__ OT,
                                                const short* __restrict__ WO,
                                                const float* __restrict__ bias,
                                                const float* __restrict__ resid,
                                                float* __restrict__ out) {
  int bx = blockIdx.x;  // o-block 0..3
  int by = blockIdx.y;  // s-block 0..63
  int bz = blockIdx.z;  // b
  int tid = threadIdx.x;
  int w = tid >> 6, lane = tid & 63;
  int sl = lane & 15, kg = lane >> 4;
  const short* Ar = OT + ((size_t)bz * SDIM + by * 64 + w * 16 + sl) * CDIM + kg * 8;
  const short* Br = WO + (size_t)(bx * 64 + sl) * CDIM + kg * 8;
  f32x4 zero = {0.f, 0.f, 0.f, 0.f};
  f32x4 acc[4] = {zero, zero, zero, zero};
#pragma unroll
  for (int kk = 0; kk < 8; ++kk) {
    bf16x8 a = *(const bf16x8*)(Ar + kk * 32);
#pragma unroll
    for (int nb = 0; nb < 4; ++nb) {
      bf16x8 bfr = *(const bf16x8*)(Br + (size_t)nb * 16 * CDIM + kk * 32);
      acc[nb] = MFMA(a, bfr, acc[nb]);
    }
  }
  int s = by * 64 + w * 16 + kg * 4;
#pragma unroll
  for (int nb = 0; nb < 4; ++nb) {
    int o = bx * 64 + nb * 16 + sl;
    size_t idx = ((size_t)bz * CDIM + o) * SDIM + s;
    float4 rr = *(const float4*)(resid + idx);
    float bo = bias[o];
    float4 ov;
    ov.x = acc[nb][0] + bo + rr.x;
    ov.y = acc[nb][1] + bo + rr.y;
    ov.z = acc[nb][2] + bo + rr.z;
    ov.w = acc[nb][3] + bo + rr.w;
    *(float4*)(out + idx) = ov;
  }
}

extern "C" void kernel_launch(void* const* d_in, const int* in_sizes, int n_in,
                              void* d_out, int out_size, void* d_ws, size_t ws_size,
                              hipStream_t stream) {
  const float* x = (const float*)d_in[0];
  const float* gamma = (const float*)d_in[1];
  const float* beta = (const float*)d_in[2];
  const float* wqkv = (const float*)d_in[3];
  const float* wout = (const float*)d_in[4];
  const float* bout = (const float*)d_in[5];
  float* out = (float*)d_out;

  // ws (shorts): wq_bf | wo_bf | normedT | qkv | attnoT
  short* wq_bf = (short*)d_ws;
  short* wo_bf = wq_bf + 768 * 256;
  short* normedT = wo_bf + 256 * 256;
  short* qkvb = normedT + (size_t)2 * SDIM * CDIM;
  short* attnoT = qkvb + (size_t)2 * 768 * SDIM;

  hipLaunchKernelGGL(cvt_weights_k, dim3(768), dim3(256), 0, stream, wqkv, wout, wq_bf, wo_bf);
  hipLaunchKernelGGL(groupnorm_k, dim3(64), dim3(256), 0, stream, x, gamma, beta, normedT);
  hipLaunchKernelGGL(gemm_qkv, dim3(12, 64, 2), dim3(256), 0, stream, wq_bf, normedT, qkvb);
  hipLaunchKernelGGL(attn_k, dim3(256), dim3(1024), 0, stream, qkvb, attnoT);
  hipLaunchKernelGGL(gemm_out, dim3(4, 64, 2), dim3(256), 0, stream, attnoT, wo_bf, bout, x, out);
}

// Round 5
// 110.949 us; speedup vs baseline: 1.3520x; 1.3520x over previous
//
#include <hip/hip_runtime.h>
#include <hip/hip_bf16.h>
#include <cstdint>
#include <cstddef>

#define SDIM 4096
#define CDIM 256
#define HSZ (64 * 4096)  // shorts per 64x4096 panel

typedef __attribute__((ext_vector_type(8))) short bf16x8;
typedef __attribute__((ext_vector_type(8))) __bf16 bfv8;
typedef __attribute__((ext_vector_type(4))) float f32x4;
typedef __attribute__((ext_vector_type(16))) float f32x16;

__device__ __forceinline__ short bfc(float f) { return __builtin_bit_cast(short, (__bf16)f); }
__device__ __forceinline__ short4 pk4(float a, float b, float c, float d) {
  short4 r; r.x = bfc(a); r.y = bfc(b); r.z = bfc(c); r.w = bfc(d); return r;
}
__device__ __forceinline__ unsigned pkbf(float lo, float hi) {
  unsigned ulo = (unsigned short)__builtin_bit_cast(short, (__bf16)lo);
  unsigned uhi = (unsigned short)__builtin_bit_cast(short, (__bf16)hi);
  return (uhi << 16) | ulo;
}
__device__ __forceinline__ f32x4 MFMA(bf16x8 a, bf16x8 b, f32x4 c) {
  return __builtin_amdgcn_mfma_f32_16x16x32_bf16(
      __builtin_bit_cast(bfv8, a), __builtin_bit_cast(bfv8, b), c, 0, 0, 0);
}
__device__ __forceinline__ f32x16 MFMA32(bf16x8 a, bf16x8 b, f32x16 c) {
  return __builtin_amdgcn_mfma_f32_32x32x16_bf16(
      __builtin_bit_cast(bfv8, a), __builtin_bit_cast(bfv8, b), c, 0, 0, 0);
}

// log2(e) / sqrt(256): folded into Q at GEMM epilogue; softmax uses exp2 directly.
#define SCQ 0.09016844f

// ---------------- weight fp32 -> bf16 ----------------
__global__ void cvt_weights_k(const float* __restrict__ wq, const float* __restrict__ wo,
                              short* __restrict__ wqb, short* __restrict__ wob) {
  int i = blockIdx.x * 256 + threadIdx.x;
  if (i < 768 * 256) wqb[i] = bfc(wq[i]);
  if (i < 256 * 256) wob[i] = bfc(wo[i]);
}

// ---------------- group norm -> normed^T[s][c] (bf16) ----------------
__global__ __launch_bounds__(256) void groupnorm_k(
    const float* __restrict__ x, const float* __restrict__ gamma,
    const float* __restrict__ beta, short* __restrict__ normedT) {
  int bg = blockIdx.x;  // b*32 + g
  int g = bg & 31, b = bg >> 5;
  const float* xg = x + (size_t)bg * 8 * SDIM;
  const float4* xv = (const float4*)xg;
  int tid = threadIdx.x;
  float sum = 0.f, sq = 0.f;
#pragma unroll 4
  for (int i = 0; i < 32; ++i) {
    float4 v = xv[tid + i * 256];
    sum += (v.x + v.y) + (v.z + v.w);
    sq += (v.x * v.x + v.y * v.y) + (v.z * v.z + v.w * v.w);
  }
#pragma unroll
  for (int m = 1; m < 64; m <<= 1) {
    sum += __shfl_xor(sum, m);
    sq += __shfl_xor(sq, m);
  }
  __shared__ float red[8];
  if ((tid & 63) == 0) { red[(tid >> 6) * 2] = sum; red[(tid >> 6) * 2 + 1] = sq; }
  __syncthreads();
  float s = red[0] + red[2] + red[4] + red[6];
  float q = red[1] + red[3] + red[5] + red[7];
  float mean = s * (1.f / 32768.f);
  float var = q * (1.f / 32768.f) - mean * mean;
  float rstd = rsqrtf(var + 1e-5f);
  float ga[8], be[8];
#pragma unroll
  for (int c = 0; c < 8; ++c) {
    ga[c] = gamma[g * 8 + c] * rstd;
    be[c] = beta[g * 8 + c] - mean * ga[c];
  }
  short* nt = normedT + (size_t)b * SDIM * CDIM + g * 8;
  for (int i = 0; i < 16; ++i) {
    int sidx = tid + i * 256;
    float v[8];
#pragma unroll
    for (int c = 0; c < 8; ++c) v[c] = xg[(size_t)c * SDIM + sidx] * ga[c] + be[c];
    union { short4 h[2]; bf16x8 v8; } o;
    o.h[0] = pk4(v[0], v[1], v[2], v[3]);
    o.h[1] = pk4(v[4], v[5], v[6], v[7]);
    *(bf16x8*)(nt + (size_t)sidx * CDIM) = o.v8;
  }
}

// ---------------- QKV GEMM (LDS-free): A=W rows, B=normed^T rows, D[o][s] ------------
__global__ __launch_bounds__(256) void gemm_qkv(const short* __restrict__ W,
                                                const short* __restrict__ XT,
                                                short* __restrict__ qkv) {
  int bx = blockIdx.x;           // o-block 0..11
  int by = blockIdx.y;           // s-block 0..63
  int bz = blockIdx.z;           // b
  int tid = threadIdx.x;
  int w = tid >> 6, lane = tid & 63;
  int sl = lane & 15, kg = lane >> 4;
  const short* Wr = W + (size_t)(bx * 64 + w * 16 + sl) * CDIM + kg * 8;
  const short* Xr = XT + ((size_t)bz * SDIM + by * 64 + sl) * CDIM + kg * 8;
  f32x4 zero = {0.f, 0.f, 0.f, 0.f};
  f32x4 acc[4] = {zero, zero, zero, zero};
#pragma unroll
  for (int kk = 0; kk < 8; ++kk) {
    bf16x8 a = *(const bf16x8*)(Wr + kk * 32);
#pragma unroll
    for (int nb = 0; nb < 4; ++nb) {
      bf16x8 bfr = *(const bf16x8*)(Xr + (size_t)nb * 16 * CDIM + kk * 32);
      acc[nb] = MFMA(a, bfr, acc[nb]);
    }
  }
  int n = bx / 3, sub = bx % 3;
  size_t hbase = (size_t)(bz * 4 + n) * 3 * HSZ;
  if (sub == 0) {
    short* qt = qkv + hbase;
#pragma unroll
    for (int nb = 0; nb < 4; ++nb) {
      int s = by * 64 + nb * 16 + sl;
      *(short4*)(qt + (size_t)s * 64 + w * 16 + kg * 4) =
          pk4(acc[nb][0] * SCQ, acc[nb][1] * SCQ, acc[nb][2] * SCQ, acc[nb][3] * SCQ);
    }
  } else if (sub == 1) {
    short* kt = qkv + hbase + HSZ;
#pragma unroll
    for (int nb = 0; nb < 4; ++nb) {
      int s = by * 64 + nb * 16 + sl;
      *(short4*)(kt + (size_t)s * 64 + w * 16 + kg * 4) =
          pk4(acc[nb][0], acc[nb][1], acc[nb][2], acc[nb][3]);
    }
  } else {
    short* vp = qkv + hbase + 2 * HSZ;
#pragma unroll
    for (int nb = 0; nb < 4; ++nb) {
      int s = by * 64 + nb * 16 + sl;
#pragma unroll
      for (int r = 0; r < 4; ++r)
        vp[(size_t)(w * 16 + kg * 4 + r) * SDIM + s] = bfc(acc[nb][r]);
    }
  }
}

// ---------------- flash attention: 512 thr = 4 sgrp x 2 thalf, 32x32x16 MFMA ---------
// K^T and V LDS-staged (stride-72 rows: conflict-free b128), double-buffered, register
// prefetch one step ahead. P stays in registers (pk + permlane32_swap). No online max
// (scores bounded, Q pre-scaled by log2e/16); exp2-domain softmax.
#define ZERO16 {0.f,0.f,0.f,0.f,0.f,0.f,0.f,0.f,0.f,0.f,0.f,0.f,0.f,0.f,0.f,0.f}
#define TSTR 72           // LDS row stride (shorts): 144B -> +4 banks/row
#define TILE (64 * TSTR)  // 4608 shorts per 64x64 tile
__global__ __launch_bounds__(512, 2) void attn_k(const short* __restrict__ qkv,
                                                 short* __restrict__ attnoT) {
  __shared__ short smem[4 * 2 * TILE];  // [thalf][buf][K|V] = 73728 shorts = 72KB

  int blk = blockIdx.x;
  int nb = blk & 7;      // (b*4+n) — XCD-grouped for L2 locality
  int sblk = blk >> 3;   // 0..31
  int tid = threadIdx.x;
  int w = tid >> 6, lane = tid & 63;
  int l5 = lane & 31, h = lane >> 5;
  int sgrp = w & 3, thalf = w >> 2;

  size_t hbase = (size_t)nb * 3 * HSZ;
  const short* qt = qkv + hbase;
  const short* kt = qkv + hbase + HSZ;   // K^T [t][d]
  const short* vp = qkv + hbase + 2 * HSZ;  // V [d][t]

  int s0w = sblk * 128 + sgrp * 32;

  // Q fragments (B operand): col s = l5, k = d = kc*16 + h*8 + j
  bf16x8 qf[4];
#pragma unroll
  for (int kc = 0; kc < 4; ++kc)
    qf[kc] = *(const bf16x8*)(qt + (size_t)(s0w + l5) * 64 + kc * 16 + h * 8);

  // staging ids (per thalf group of 256 threads)
  int ltid = tid & 255;
  int srow = ltid >> 3;   // row 0..31 (+32)
  int sch = ltid & 7;     // 8-short chunk
  int tbase = thalf * 2048;
  short* sbase = smem + thalf * 2 * 2 * TILE;

  // prefetch tile 0 into regs
  bf16x8 kreg0, kreg1, vreg0, vreg1;
  kreg0 = *(const bf16x8*)(kt + (size_t)(tbase + srow) * 64 + sch * 8);
  kreg1 = *(const bf16x8*)(kt + (size_t)(tbase + srow + 32) * 64 + sch * 8);
  vreg0 = *(const bf16x8*)(vp + (size_t)srow * SDIM + tbase + sch * 8);
  vreg1 = *(const bf16x8*)(vp + (size_t)(srow + 32) * SDIM + tbase + sch * 8);
  {
    short* kb = sbase;
    short* vb = sbase + TILE;
    *(bf16x8*)(kb + srow * TSTR + sch * 8) = kreg0;
    *(bf16x8*)(kb + (srow + 32) * TSTR + sch * 8) = kreg1;
    *(bf16x8*)(vb + srow * TSTR + sch * 8) = vreg0;
    *(bf16x8*)(vb + (srow + 32) * TSTR + sch * 8) = vreg1;
  }
  __syncthreads();

  f32x16 acc_o0 = ZERO16, acc_o1 = ZERO16;
  float l_run = 0.f;

  for (int step = 0; step < 32; ++step) {
    short* kbuf = sbase + (step & 1) * 2 * TILE;
    short* vbuf = kbuf + TILE;
    // prefetch next tile (global -> regs), hidden under compute
    if (step + 1 < 32) {
      int t1 = tbase + (step + 1) * 64;
      kreg0 = *(const bf16x8*)(kt + (size_t)(t1 + srow) * 64 + sch * 8);
      kreg1 = *(const bf16x8*)(kt + (size_t)(t1 + srow + 32) * 64 + sch * 8);
      vreg0 = *(const bf16x8*)(vp + (size_t)srow * SDIM + t1 + sch * 8);
      vreg1 = *(const bf16x8*)(vp + (size_t)(srow + 32) * SDIM + t1 + sch * 8);
    }

    // QK^T: A = K^T rows (LDS), B = Q regs. D: col s=l5, row t=(r&3)+8*(r>>2)+4h
    f32x16 accs0 = ZERO16, accs1 = ZERO16;
#pragma unroll
    for (int kc = 0; kc < 4; ++kc) {
      bf16x8 k0 = *(const bf16x8*)(kbuf + l5 * TSTR + (kc * 2 + h) * 8);
      bf16x8 k1 = *(const bf16x8*)(kbuf + (32 + l5) * TSTR + (kc * 2 + h) * 8);
      accs0 = MFMA32(k0, qf[kc], accs0);
      accs1 = MFMA32(k1, qf[kc], accs1);
    }

    // softmax: P = exp2(score), no max subtraction
    float p0[16], p1[16];
    float ts = 0.f;
#pragma unroll
    for (int r = 0; r < 16; ++r) { p0[r] = __builtin_amdgcn_exp2f(accs0[r]); ts += p0[r]; }
#pragma unroll
    for (int r = 0; r < 16; ++r) { p1[r] = __builtin_amdgcn_exp2f(accs1[r]); ts += p1[r]; }
    l_run += ts;

    // P -> A-frag via pack + permlane32_swap; PV: B = V rows from LDS
#define PV_TC(pp, tcb, tc)                                                        \
    {                                                                             \
      unsigned a0 = pkbf(pp[8 * tcb + 0], pp[8 * tcb + 1]);                       \
      unsigned a1 = pkbf(pp[8 * tcb + 2], pp[8 * tcb + 3]);                       \
      unsigned b0 = pkbf(pp[8 * tcb + 4], pp[8 * tcb + 5]);                       \
      unsigned b1 = pkbf(pp[8 * tcb + 6], pp[8 * tcb + 7]);                       \
      asm volatile("v_permlane32_swap_b32 %0, %1" : "+v"(a0), "+v"(b0));          \
      asm volatile("v_permlane32_swap_b32 %0, %1" : "+v"(a1), "+v"(b1));          \
      union { unsigned u[4]; bf16x8 v; } F;                                       \
      F.u[0] = a0; F.u[1] = a1; F.u[2] = b0; F.u[3] = b1;                         \
      int c8 = (tc * 2 + h) * 8;                                                  \
      bf16x8 v0 = *(const bf16x8*)(vbuf + l5 * TSTR + c8);                        \
      bf16x8 v1 = *(const bf16x8*)(vbuf + (32 + l5) * TSTR + c8);                 \
      acc_o0 = MFMA32(F.v, v0, acc_o0);                                           \
      acc_o1 = MFMA32(F.v, v1, acc_o1);                                           \
    }
    PV_TC(p0, 0, 0)
    PV_TC(p0, 1, 1)
    PV_TC(p1, 0, 2)
    PV_TC(p1, 1, 3)
#undef PV_TC

    // stage next tile into the other buffer (waits vmcnt on prefetch)
    if (step + 1 < 32) {
      short* kn = sbase + ((step + 1) & 1) * 2 * TILE;
      short* vn = kn + TILE;
      *(bf16x8*)(kn + srow * TSTR + sch * 8) = kreg0;
      *(bf16x8*)(kn + (srow + 32) * TSTR + sch * 8) = kreg1;
      *(bf16x8*)(vn + srow * TSTR + sch * 8) = vreg0;
      *(bf16x8*)(vn + (srow + 32) * TSTR + sch * 8) = vreg1;
    }
    __syncthreads();
  }

  // combine h halves of l (each lane then has full sum over its thalf's t)
  l_run += __shfl_xor(l_run, 32);

  // cross-thalf merge via LDS (reuse tile space)
  float* accbuf = (float*)smem;  // 4 sgrp x 64 lanes x 33 f32 = 33792 B
  float* lbuf = accbuf + 4 * 64 * 33;
  float* dst = accbuf + (size_t)(sgrp * 64 + lane) * 33;
  __syncthreads();
  if (thalf) {
#pragma unroll
    for (int i = 0; i < 16; ++i) { dst[i] = acc_o0[i]; dst[16 + i] = acc_o1[i]; }
    dst[32] = l_run;
  }
  __syncthreads();
  if (!thalf) {
#pragma unroll
    for (int i = 0; i < 16; ++i) { acc_o0[i] += dst[i]; acc_o1[i] += dst[16 + i]; }
    l_run += dst[32];
    if (h == 0) lbuf[sgrp * 32 + l5] = l_run;
  }
  __syncthreads();
  if (!thalf) {
    int n = nb & 3, b = nb >> 2;
#pragma unroll
    for (int r = 0; r < 16; ++r) {
      int srw = (r & 3) + 8 * (r >> 2) + 4 * h;
      float inv = 1.f / lbuf[sgrp * 32 + srw];
      int sg = s0w + srw;
      size_t rowb = ((size_t)b * SDIM + sg) * CDIM + n * 64;
      attnoT[rowb + l5] = bfc(acc_o0[r] * inv);
      attnoT[rowb + 32 + l5] = bfc(acc_o1[r] * inv);
    }
  }
}

// ---------------- final GEMM (LDS-free): A=O^T rows, B=W_out rows, D[s][o] -----------
__global__ __launch_bounds__(256) void gemm_out(const short* __restrict__ OT,
                                                const short* __restrict__ WO,
                                                const float* __restrict__ bias,
                                                const float* __restrict__ resid,
                                                float* __restrict__ out) {
  int bx = blockIdx.x;  // o-block 0..3
  int by = blockIdx.y;  // s-block 0..63
  int bz = blockIdx.z;  // b
  int tid = threadIdx.x;
  int w = tid >> 6, lane = tid & 63;
  int sl = lane & 15, kg = lane >> 4;
  const short* Ar = OT + ((size_t)bz * SDIM + by * 64 + w * 16 + sl) * CDIM + kg * 8;
  const short* Br = WO + (size_t)(bx * 64 + sl) * CDIM + kg * 8;
  f32x4 zero = {0.f, 0.f, 0.f, 0.f};
  f32x4 acc[4] = {zero, zero, zero, zero};
#pragma unroll
  for (int kk = 0; kk < 8; ++kk) {
    bf16x8 a = *(const bf16x8*)(Ar + kk * 32);
#pragma unroll
    for (int nb = 0; nb < 4; ++nb) {
      bf16x8 bfr = *(const bf16x8*)(Br + (size_t)nb * 16 * CDIM + kk * 32);
      acc[nb] = MFMA(a, bfr, acc[nb]);
    }
  }
  int s = by * 64 + w * 16 + kg * 4;
#pragma unroll
  for (int nb = 0; nb < 4; ++nb) {
    int o = bx * 64 + nb * 16 + sl;
    size_t idx = ((size_t)bz * CDIM + o) * SDIM + s;
    float4 rr = *(const float4*)(resid + idx);
    float bo = bias[o];
    float4 ov;
    ov.x = acc[nb][0] + bo + rr.x;
    ov.y = acc[nb][1] + bo + rr.y;
    ov.z = acc[nb][2] + bo + rr.z;
    ov.w = acc[nb][3] + bo + rr.w;
    *(float4*)(out + idx) = ov;
  }
}

extern "C" void kernel_launch(void* const* d_in, const int* in_sizes, int n_in,
                              void* d_out, int out_size, void* d_ws, size_t ws_size,
                              hipStream_t stream) {
  const float* x = (const float*)d_in[0];
  const float* gamma = (const float*)d_in[1];
  const float* beta = (const float*)d_in[2];
  const float* wqkv = (const float*)d_in[3];
  const float* wout = (const float*)d_in[4];
  const float* bout = (const float*)d_in[5];
  float* out = (float*)d_out;

  // ws (shorts): wq_bf | wo_bf | normedT | qkv | attnoT
  short* wq_bf = (short*)d_ws;
  short* wo_bf = wq_bf + 768 * 256;
  short* normedT = wo_bf + 256 * 256;
  short* qkvb = normedT + (size_t)2 * SDIM * CDIM;
  short* attnoT = qkvb + (size_t)2 * 768 * SDIM;

  hipLaunchKernelGGL(cvt_weights_k, dim3(768), dim3(256), 0, stream, wqkv, wout, wq_bf, wo_bf);
  hipLaunchKernelGGL(groupnorm_k, dim3(64), dim3(256), 0, stream, x, gamma, beta, normedT);
  hipLaunchKernelGGL(gemm_qkv, dim3(12, 64, 2), dim3(256), 0, stream, wq_bf, normedT, qkvb);
  hipLaunchKernelGGL(attn_k, dim3(256), dim3(512), 0, stream, qkvb, attnoT);
  hipLaunchKernelGGL(gemm_out, dim3(4, 64, 2), dim3(256), 0, stream, attnoT, wo_bf, bout, x, out);
}

// Round 6
// 104.410 us; speedup vs baseline: 1.4367x; 1.0626x over previous
//
#include <hip/hip_runtime.h>
#include <hip/hip_bf16.h>
#include <cstdint>
#include <cstddef>

#define SDIM 4096
#define CDIM 256
#define HSZ (64 * 4096)  // shorts per 64x4096 panel

typedef __attribute__((ext_vector_type(8))) short bf16x8;
typedef __attribute__((ext_vector_type(8))) __bf16 bfv8;
typedef __attribute__((ext_vector_type(4))) float f32x4;
typedef __attribute__((ext_vector_type(16))) float f32x16;

__device__ __forceinline__ float bf2f(short u) {
  union { uint32_t i; float f; } v; v.i = ((uint32_t)(uint16_t)u) << 16; return v.f;
}
__device__ __forceinline__ short bfc(float f) { return __builtin_bit_cast(short, (__bf16)f); }
__device__ __forceinline__ short4 pk4(float a, float b, float c, float d) {
  short4 r; r.x = bfc(a); r.y = bfc(b); r.z = bfc(c); r.w = bfc(d); return r;
}
__device__ __forceinline__ unsigned pkbf(float lo, float hi) {
  unsigned ulo = (unsigned short)__builtin_bit_cast(short, (__bf16)lo);
  unsigned uhi = (unsigned short)__builtin_bit_cast(short, (__bf16)hi);
  return (uhi << 16) | ulo;
}
__device__ __forceinline__ f32x4 MFMA(bf16x8 a, bf16x8 b, f32x4 c) {
  return __builtin_amdgcn_mfma_f32_16x16x32_bf16(
      __builtin_bit_cast(bfv8, a), __builtin_bit_cast(bfv8, b), c, 0, 0, 0);
}
__device__ __forceinline__ f32x16 MFMA32(bf16x8 a, bf16x8 b, f32x16 c) {
  return __builtin_amdgcn_mfma_f32_32x32x16_bf16(
      __builtin_bit_cast(bfv8, a), __builtin_bit_cast(bfv8, b), c, 0, 0, 0);
}

// log2(e) / sqrt(256): folded into Q at GEMM epilogue; softmax uses exp2 directly.
#define SCQ 0.09016844f

// ---------------- prep1: GN partial sums (blocks 0..511) + weight cvt (512..767) -----
__global__ __launch_bounds__(256) void prep1_k(
    const float* __restrict__ x, const float* __restrict__ wq,
    const float* __restrict__ wo, float* __restrict__ gnws,
    short* __restrict__ wqb, short* __restrict__ wob) {
  __shared__ float red[8];
  int blk = blockIdx.x;
  int tid = threadIdx.x;
  if (blk < 512) {
    // one (b,g) channel-chunk: bg = blk>>3, channel-in-group = blk&7 (4096 elems)
    const float4* xv = (const float4*)(x + (size_t)(blk >> 3) * 32768 + (blk & 7) * 4096);
    float sum = 0.f, sq = 0.f;
#pragma unroll
    for (int i = 0; i < 4; ++i) {
      float4 v = xv[tid + i * 256];
      sum += (v.x + v.y) + (v.z + v.w);
      sq += (v.x * v.x + v.y * v.y) + (v.z * v.z + v.w * v.w);
    }
#pragma unroll
    for (int m = 1; m < 64; m <<= 1) {
      sum += __shfl_xor(sum, m);
      sq += __shfl_xor(sq, m);
    }
    if ((tid & 63) == 0) { red[(tid >> 6) * 2] = sum; red[(tid >> 6) * 2 + 1] = sq; }
    __syncthreads();
    if (tid == 0) {
      gnws[blk * 2] = red[0] + red[2] + red[4] + red[6];
      gnws[blk * 2 + 1] = red[1] + red[3] + red[5] + red[7];
    }
  } else {
    int i = (blk - 512) * 256 + tid;  // float4 index
    if (i < 49152) {
      float4 v = ((const float4*)wq)[i];
      ((short4*)wqb)[i] = pk4(v.x, v.y, v.z, v.w);
    } else {
      float4 v = ((const float4*)wo)[i - 49152];
      ((short4*)wob)[i - 49152] = pk4(v.x, v.y, v.z, v.w);
    }
  }
}

// ---------------- GN apply -> normed^T[s][c] (bf16), 512 blocks ----------------------
__global__ __launch_bounds__(256) void gn_apply_k(
    const float* __restrict__ x, const float* __restrict__ gnws,
    const float* __restrict__ gamma, const float* __restrict__ beta,
    short* __restrict__ normedT) {
  int blk = blockIdx.x;
  int bg = blk >> 3, sc = blk & 7;
  int g = bg & 31, b = bg >> 5;
  int tid = threadIdx.x;
  float sum = 0.f, sq = 0.f;
#pragma unroll
  for (int c = 0; c < 8; ++c) {
    sum += gnws[(bg * 8 + c) * 2];
    sq += gnws[(bg * 8 + c) * 2 + 1];
  }
  float mean = sum * (1.f / 32768.f);
  float var = sq * (1.f / 32768.f) - mean * mean;
  float rstd = rsqrtf(var + 1e-5f);
  float ga[8], be[8];
#pragma unroll
  for (int c = 0; c < 8; ++c) {
    ga[c] = gamma[g * 8 + c] * rstd;
    be[c] = beta[g * 8 + c] - mean * ga[c];
  }
  const float* xg = x + (size_t)bg * 32768;
  short* nt = normedT + (size_t)b * SDIM * CDIM + g * 8;
#pragma unroll
  for (int it = 0; it < 2; ++it) {
    int s = sc * 512 + it * 256 + tid;
    float v[8];
#pragma unroll
    for (int c = 0; c < 8; ++c) v[c] = xg[c * 4096 + s] * ga[c] + be[c];
    union { short4 h[2]; bf16x8 v8; } o;
    o.h[0] = pk4(v[0], v[1], v[2], v[3]);
    o.h[1] = pk4(v[4], v[5], v[6], v[7]);
    *(bf16x8*)(nt + (size_t)s * CDIM) = o.v8;
  }
}

// ---------------- QKV GEMM (LDS-free): A=W rows, B=normed^T rows, D[o][s] ------------
__global__ __launch_bounds__(256) void gemm_qkv(const short* __restrict__ W,
                                                const short* __restrict__ XT,
                                                short* __restrict__ qkv) {
  int bx = blockIdx.x;           // o-block 0..11
  int by = blockIdx.y;           // s-block 0..63
  int bz = blockIdx.z;           // b
  int tid = threadIdx.x;
  int w = tid >> 6, lane = tid & 63;
  int sl = lane & 15, kg = lane >> 4;
  const short* Wr = W + (size_t)(bx * 64 + w * 16 + sl) * CDIM + kg * 8;
  const short* Xr = XT + ((size_t)bz * SDIM + by * 64 + sl) * CDIM + kg * 8;
  f32x4 zero = {0.f, 0.f, 0.f, 0.f};
  f32x4 acc[4] = {zero, zero, zero, zero};
#pragma unroll
  for (int kk = 0; kk < 8; ++kk) {
    bf16x8 a = *(const bf16x8*)(Wr + kk * 32);
#pragma unroll
    for (int nb = 0; nb < 4; ++nb) {
      bf16x8 bfr = *(const bf16x8*)(Xr + (size_t)nb * 16 * CDIM + kk * 32);
      acc[nb] = MFMA(a, bfr, acc[nb]);
    }
  }
  int n = bx / 3, sub = bx % 3;
  size_t hbase = (size_t)(bz * 4 + n) * 3 * HSZ;
  if (sub == 0) {
    short* qt = qkv + hbase;
#pragma unroll
    for (int nb = 0; nb < 4; ++nb) {
      int s = by * 64 + nb * 16 + sl;
      *(short4*)(qt + (size_t)s * 64 + w * 16 + kg * 4) =
          pk4(acc[nb][0] * SCQ, acc[nb][1] * SCQ, acc[nb][2] * SCQ, acc[nb][3] * SCQ);
    }
  } else if (sub == 1) {
    short* kt = qkv + hbase + HSZ;
#pragma unroll
    for (int nb = 0; nb < 4; ++nb) {
      int s = by * 64 + nb * 16 + sl;
      *(short4*)(kt + (size_t)s * 64 + w * 16 + kg * 4) =
          pk4(acc[nb][0], acc[nb][1], acc[nb][2], acc[nb][3]);
    }
  } else {
    short* vp = qkv + hbase + 2 * HSZ;
#pragma unroll
    for (int nb = 0; nb < 4; ++nb) {
      int s = by * 64 + nb * 16 + sl;
#pragma unroll
      for (int r = 0; r < 4; ++r)
        vp[(size_t)(w * 16 + kg * 4 + r) * SDIM + s] = bfc(acc[nb][r]);
    }
  }
}

// ---------------- flash attention: 512 blocks (t-split x2), 512 thr ------------------
// Block = 4 sgrp x 2 thalf waves; covers 128 s-cols and 2048 t (thalf: 1024 each).
// K^T and V LDS-staged (stride-72, conflict-free), double-buffered, reg prefetch.
// P in registers (pk + permlane32_swap). No online max (Q pre-scaled by log2e/16).
// Writes UNNORMALIZED partial O' (bf16) to po[tb][b][s][c] and l to pl[tb][bn][s].
#define ZERO16 {0.f,0.f,0.f,0.f,0.f,0.f,0.f,0.f,0.f,0.f,0.f,0.f,0.f,0.f,0.f,0.f}
#define TSTR 72           // LDS row stride (shorts): 144B -> +4 banks/row
#define TILE (64 * TSTR)  // 4608 shorts per 64x64 tile
__global__ __launch_bounds__(512, 2) void attn_k(const short* __restrict__ qkv,
                                                 short* __restrict__ po,
                                                 float* __restrict__ pl) {
  __shared__ short smem[4 * 2 * TILE];  // [thalf][buf][K|V] = 72KB

  int blk = blockIdx.x;
  int nb = blk & 7;          // (b*4+n) — XCD-grouped for L2 locality
  int tb = (blk >> 3) & 1;   // t-half of the whole range
  int sblk = blk >> 4;       // 0..31
  int tid = threadIdx.x;
  int w = tid >> 6, lane = tid & 63;
  int l5 = lane & 31, h = lane >> 5;
  int sgrp = w & 3, thalf = w >> 2;

  size_t hbase = (size_t)nb * 3 * HSZ;
  const short* qt = qkv + hbase;
  const short* kt = qkv + hbase + HSZ;      // K^T [t][d]
  const short* vp = qkv + hbase + 2 * HSZ;  // V [d][t]

  int s0w = sblk * 128 + sgrp * 32;

  // Q fragments (B operand): col s = l5, k = d = kc*16 + h*8 + j
  bf16x8 qf[4];
#pragma unroll
  for (int kc = 0; kc < 4; ++kc)
    qf[kc] = *(const bf16x8*)(qt + (size_t)(s0w + l5) * 64 + kc * 16 + h * 8);

  // staging ids (per thalf group of 256 threads)
  int ltid = tid & 255;
  int srow = ltid >> 3;   // row 0..31 (+32)
  int sch = ltid & 7;     // 8-short chunk
  int tbase = (tb * 2 + thalf) * 1024;
  short* sbase = smem + thalf * 2 * 2 * TILE;

  // prefetch tile 0 into regs, stage
  bf16x8 kreg0, kreg1, vreg0, vreg1;
  kreg0 = *(const bf16x8*)(kt + (size_t)(tbase + srow) * 64 + sch * 8);
  kreg1 = *(const bf16x8*)(kt + (size_t)(tbase + srow + 32) * 64 + sch * 8);
  vreg0 = *(const bf16x8*)(vp + (size_t)srow * SDIM + tbase + sch * 8);
  vreg1 = *(const bf16x8*)(vp + (size_t)(srow + 32) * SDIM + tbase + sch * 8);
  {
    short* kb = sbase;
    short* vb = sbase + TILE;
    *(bf16x8*)(kb + srow * TSTR + sch * 8) = kreg0;
    *(bf16x8*)(kb + (srow + 32) * TSTR + sch * 8) = kreg1;
    *(bf16x8*)(vb + srow * TSTR + sch * 8) = vreg0;
    *(bf16x8*)(vb + (srow + 32) * TSTR + sch * 8) = vreg1;
  }
  __syncthreads();

  f32x16 acc_o0 = ZERO16, acc_o1 = ZERO16;
  float l_run = 0.f;

  for (int step = 0; step < 16; ++step) {
    short* kbuf = sbase + (step & 1) * 2 * TILE;
    short* vbuf = kbuf + TILE;
    // prefetch next tile (global -> regs), hidden under compute
    if (step + 1 < 16) {
      int t1 = tbase + (step + 1) * 64;
      kreg0 = *(const bf16x8*)(kt + (size_t)(t1 + srow) * 64 + sch * 8);
      kreg1 = *(const bf16x8*)(kt + (size_t)(t1 + srow + 32) * 64 + sch * 8);
      vreg0 = *(const bf16x8*)(vp + (size_t)srow * SDIM + t1 + sch * 8);
      vreg1 = *(const bf16x8*)(vp + (size_t)(srow + 32) * SDIM + t1 + sch * 8);
    }

    // QK^T: A = K^T rows (LDS), B = Q regs. D: col s=l5, row t=(r&3)+8*(r>>2)+4h
    f32x16 accs0 = ZERO16, accs1 = ZERO16;
#pragma unroll
    for (int kc = 0; kc < 4; ++kc) {
      bf16x8 k0 = *(const bf16x8*)(kbuf + l5 * TSTR + (kc * 2 + h) * 8);
      bf16x8 k1 = *(const bf16x8*)(kbuf + (32 + l5) * TSTR + (kc * 2 + h) * 8);
      accs0 = MFMA32(k0, qf[kc], accs0);
      accs1 = MFMA32(k1, qf[kc], accs1);
    }

    // softmax: P = exp2(score), no max subtraction
    float p0[16], p1[16];
    float ts = 0.f;
#pragma unroll
    for (int r = 0; r < 16; ++r) { p0[r] = __builtin_amdgcn_exp2f(accs0[r]); ts += p0[r]; }
#pragma unroll
    for (int r = 0; r < 16; ++r) { p1[r] = __builtin_amdgcn_exp2f(accs1[r]); ts += p1[r]; }
    l_run += ts;

    // P -> A-frag via pack + permlane32_swap; PV: B = V rows from LDS
#define PV_TC(pp, tcb, tc)                                                        \
    {                                                                             \
      unsigned a0 = pkbf(pp[8 * tcb + 0], pp[8 * tcb + 1]);                       \
      unsigned a1 = pkbf(pp[8 * tcb + 2], pp[8 * tcb + 3]);                       \
      unsigned b0 = pkbf(pp[8 * tcb + 4], pp[8 * tcb + 5]);                       \
      unsigned b1 = pkbf(pp[8 * tcb + 6], pp[8 * tcb + 7]);                       \
      asm volatile("v_permlane32_swap_b32 %0, %1" : "+v"(a0), "+v"(b0));          \
      asm volatile("v_permlane32_swap_b32 %0, %1" : "+v"(a1), "+v"(b1));          \
      union { unsigned u[4]; bf16x8 v; } F;                                       \
      F.u[0] = a0; F.u[1] = a1; F.u[2] = b0; F.u[3] = b1;                         \
      int c8 = (tc * 2 + h) * 8;                                                  \
      bf16x8 v0 = *(const bf16x8*)(vbuf + l5 * TSTR + c8);                        \
      bf16x8 v1 = *(const bf16x8*)(vbuf + (32 + l5) * TSTR + c8);                 \
      acc_o0 = MFMA32(F.v, v0, acc_o0);                                           \
      acc_o1 = MFMA32(F.v, v1, acc_o1);                                           \
    }
    PV_TC(p0, 0, 0)
    PV_TC(p0, 1, 1)
    PV_TC(p1, 0, 2)
    PV_TC(p1, 1, 3)
#undef PV_TC

    // stage next tile into the other buffer
    if (step + 1 < 16) {
      short* kn = sbase + ((step + 1) & 1) * 2 * TILE;
      short* vn = kn + TILE;
      *(bf16x8*)(kn + srow * TSTR + sch * 8) = kreg0;
      *(bf16x8*)(kn + (srow + 32) * TSTR + sch * 8) = kreg1;
      *(bf16x8*)(vn + srow * TSTR + sch * 8) = vreg0;
      *(bf16x8*)(vn + (srow + 32) * TSTR + sch * 8) = vreg1;
    }
    __syncthreads();
  }

  // combine h halves of l
  l_run += __shfl_xor(l_run, 32);

  // cross-thalf merge via LDS (reuse tile space)
  float* accbuf = (float*)smem;  // 4 sgrp x 64 lanes x 33 f32
  float* dst = accbuf + (size_t)(sgrp * 64 + lane) * 33;
  __syncthreads();
  if (thalf) {
#pragma unroll
    for (int i = 0; i < 16; ++i) { dst[i] = acc_o0[i]; dst[16 + i] = acc_o1[i]; }
    dst[32] = l_run;
  }
  __syncthreads();
  if (!thalf) {
#pragma unroll
    for (int i = 0; i < 16; ++i) { acc_o0[i] += dst[i]; acc_o1[i] += dst[16 + i]; }
    l_run += dst[32];
    if (h == 0) pl[((size_t)tb * 8 + nb) * SDIM + s0w + l5] = l_run;
    int n = nb & 3, b = nb >> 2;
#pragma unroll
    for (int r = 0; r < 16; ++r) {
      int srw = (r & 3) + 8 * (r >> 2) + 4 * h;
      int sg = s0w + srw;
      size_t rowb = ((size_t)(tb * 2 + b) * SDIM + sg) * CDIM + n * 64;
      po[rowb + l5] = bfc(acc_o0[r]);
      po[rowb + 32 + l5] = bfc(acc_o1[r]);
    }
  }
}

// ---------------- final GEMM (LDS-free) with fused t-merge ---------------------------
// A[s][c] = (po0[s][c] + po1[s][c]) / (l0+l1)[b, n=c/64, s];  B = W_out rows.
// out[b][o][s] = D + bias[o] + x[b][o][s]  (fp32, float4 stores)
__global__ __launch_bounds__(256) void gemm_out(const short* __restrict__ po,
                                                const float* __restrict__ pl,
                                                const short* __restrict__ WO,
                                                const float* __restrict__ bias,
                                                const float* __restrict__ resid,
                                                float* __restrict__ out) {
  int bx = blockIdx.x;  // o-block 0..3 (64 each)
  int by = blockIdx.y;  // s-block 0..127 (32 each)
  int bz = blockIdx.z;  // b
  int tid = threadIdx.x;
  int w = tid >> 6, lane = tid & 63;
  int sl = lane & 15, kg = lane >> 4;
  int sw = w & 1, ow = w >> 1;
  int arow = by * 32 + sw * 16 + sl;  // s row of A
  const short* A0 = po + ((size_t)(0 + bz) * SDIM + arow) * CDIM + kg * 8;
  const short* A1 = po + ((size_t)(2 + bz) * SDIM + arow) * CDIM + kg * 8;
  const short* Br = WO + (size_t)(bx * 64 + ow * 32 + sl) * CDIM + kg * 8;
  float inv4[4];
#pragma unroll
  for (int n = 0; n < 4; ++n)
    inv4[n] = 1.f / (pl[(size_t)(bz * 4 + n) * SDIM + arow] +
                     pl[(size_t)(8 + bz * 4 + n) * SDIM + arow]);
  f32x4 zero = {0.f, 0.f, 0.f, 0.f};
  f32x4 acc[2] = {zero, zero};
#pragma unroll
  for (int kk = 0; kk < 8; ++kk) {
    bf16x8 a0 = *(const bf16x8*)(A0 + kk * 32);
    bf16x8 a1 = *(const bf16x8*)(A1 + kk * 32);
    float iv = inv4[kk >> 1];
    float f[8];
#pragma unroll
    for (int j = 0; j < 8; ++j) f[j] = (bf2f(a0[j]) + bf2f(a1[j])) * iv;
    union { short4 h[2]; bf16x8 v8; } A;
    A.h[0] = pk4(f[0], f[1], f[2], f[3]);
    A.h[1] = pk4(f[4], f[5], f[6], f[7]);
#pragma unroll
    for (int nb = 0; nb < 2; ++nb) {
      bf16x8 bfr = *(const bf16x8*)(Br + (size_t)nb * 16 * CDIM + kk * 32);
      acc[nb] = MFMA(A.v8, bfr, acc[nb]);
    }
  }
  int s = by * 32 + sw * 16 + kg * 4;
#pragma unroll
  for (int nb = 0; nb < 2; ++nb) {
    int o = bx * 64 + ow * 32 + nb * 16 + sl;
    size_t idx = ((size_t)bz * CDIM + o) * SDIM + s;
    float4 rr = *(const float4*)(resid + idx);
    float bo = bias[o];
    float4 ov;
    ov.x = acc[nb][0] + bo + rr.x;
    ov.y = acc[nb][1] + bo + rr.y;
    ov.z = acc[nb][2] + bo + rr.z;
    ov.w = acc[nb][3] + bo + rr.w;
    *(float4*)(out + idx) = ov;
  }
}

extern "C" void kernel_launch(void* const* d_in, const int* in_sizes, int n_in,
                              void* d_out, int out_size, void* d_ws, size_t ws_size,
                              hipStream_t stream) {
  const float* x = (const float*)d_in[0];
  const float* gamma = (const float*)d_in[1];
  const float* beta = (const float*)d_in[2];
  const float* wqkv = (const float*)d_in[3];
  const float* wout = (const float*)d_in[4];
  const float* bout = (const float*)d_in[5];
  float* out = (float*)d_out;

  // ws (shorts): wq_bf | wo_bf | normedT | qkv | po, then f32: pl | gnws  (~26MB)
  short* wq_bf = (short*)d_ws;
  short* wo_bf = wq_bf + 768 * 256;
  short* normedT = wo_bf + 256 * 256;
  short* qkvb = normedT + (size_t)2 * SDIM * CDIM;
  short* po = qkvb + (size_t)2 * 768 * SDIM;
  float* pl = (float*)(po + (size_t)2 * 2 * SDIM * CDIM);
  float* gnws = pl + 2 * 8 * SDIM;

  hipLaunchKernelGGL(prep1_k, dim3(768), dim3(256), 0, stream, x, wqkv, wout, gnws,
                     wq_bf, wo_bf);
  hipLaunchKernelGGL(gn_apply_k, dim3(512), dim3(256), 0, stream, x, gnws, gamma, beta,
                     normedT);
  hipLaunchKernelGGL(gemm_qkv, dim3(12, 64, 2), dim3(256), 0, stream, wq_bf, normedT,
                     qkvb);
  hipLaunchKernelGGL(attn_k, dim3(512), dim3(512), 0, stream, qkvb, po, pl);
  hipLaunchKernelGGL(gemm_out, dim3(4, 128, 2), dim3(256), 0, stream, po, pl, wo_bf,
                     bout, x, out);
}